// Round 13
// baseline (158.167 us; speedup 1.0000x reference)
//
#include <hip/hip_runtime.h>
#include <cstdint>
#include <cstddef>

typedef __bf16 bf16_t;
typedef bf16_t bf16x8 __attribute__((ext_vector_type(8)));
typedef float f32x4 __attribute__((ext_vector_type(4)));
typedef unsigned short u16x8 __attribute__((ext_vector_type(8)));
typedef unsigned short u16x4 __attribute__((ext_vector_type(4)));

#define SEQ 4096
#define BATCH 8
#define NTOK 32768      // BATCH*SEQ
#define NQKV 1536
#define DMODEL 512
#define NBH 64          // BATCH*HEADS
#define NCHUNK 8

__device__ __forceinline__ unsigned short f2b(float f) {
    union { float f; unsigned u; } c; c.f = f;
    unsigned u = c.u;
    u += 0x7fffu + ((u >> 16) & 1u);   // round-to-nearest-even
    return (unsigned short)(u >> 16);
}
__device__ __forceinline__ float b2f(unsigned short h) {
    union { unsigned u; float f; } c; c.u = ((unsigned)h) << 16;
    return c.f;
}
__device__ __forceinline__ float feat(float v) {   // elu(v)+1
    return v > 0.f ? v + 1.f : __expf(v);
}

// async global->LDS, 16B per lane; LDS dest is wave-uniform base + lane*16
__device__ __forceinline__ void gload16(const unsigned short* g, unsigned short* lds_base) {
    __builtin_amdgcn_global_load_lds((const __attribute__((address_space(1))) unsigned int*)g,
                                     (__attribute__((address_space(3))) unsigned int*)lds_base,
                                     16, 0, 0);
}

// ---------------- prep: fp32 -> bf16 for x and both weights ----------------
__global__ __launch_bounds__(256) void prep_kernel(const float* __restrict__ x,
                                                   const float* __restrict__ wqkv,
                                                   const float* __restrict__ wout,
                                                   unsigned short* __restrict__ xB,
                                                   unsigned short* __restrict__ wqkvB,
                                                   unsigned short* __restrict__ woutB) {
    const int stride = gridDim.x * 256;
    const int t0 = blockIdx.x * 256 + threadIdx.x;
    for (int j = t0; j < NTOK * DMODEL / 4; j += stride) {
        f32x4 v = ((const f32x4*)x)[j];
        u16x4 o = { f2b(v[0]), f2b(v[1]), f2b(v[2]), f2b(v[3]) };
        ((u16x4*)xB)[j] = o;
    }
    for (int j = t0; j < NQKV * DMODEL / 4; j += stride) {
        f32x4 v = ((const f32x4*)wqkv)[j];
        u16x4 o = { f2b(v[0]), f2b(v[1]), f2b(v[2]), f2b(v[3]) };
        ((u16x4*)wqkvB)[j] = o;
    }
    for (int j = t0; j < DMODEL * DMODEL / 4; j += stride) {
        f32x4 v = ((const f32x4*)wout)[j];
        u16x4 o = { f2b(v[0]), f2b(v[1]), f2b(v[2]), f2b(v[3]) };
        ((u16x4*)woutB)[j] = o;
    }
}

// ---------------- MFMA GEMM: C = A @ B^T, A bf16 [M][K], B bf16 [N][K] ----------------
// R8-proven structure: 256x128 tile, 8 waves (4M x 2N), BK=64. Counted-vmcnt pipeline:
// A double-buffered (prefetch 2 iters ahead), B single-buffered (prefetch 1 iter).
// LDS = 80 KiB. T2 XOR-swizzle (0 conflicts), T1 XCD swizzle.
// NEW vs R8: k/v epilogue bounces the 128(hd)x256(n) tile through the dead As_ LDS and
// flushes with coalesced 16B/lane stores (was: 8B x 64-line scatter per store).
// MODE 0: feature-map epilogue -> qF [tok][512] bf16; kT/vT [bh][d][4096] bf16 (transposed)
// MODE 1: +bias epilogue -> fp32 out [tok][512]   (Ck/Cv unused)
template <int MODE>
__global__ __launch_bounds__(512) void gemm_kernel(const unsigned short* __restrict__ A,
                                                   const unsigned short* __restrict__ B,
                                                   void* __restrict__ Cq,
                                                   unsigned short* __restrict__ Ck,
                                                   unsigned short* __restrict__ Cv,
                                                   const float* __restrict__ bias,
                                                   int M, int N, int K, int nColBlocks) {
    __shared__ __align__(16) unsigned short As_[2][256 * 64];   // 64 KiB (dbuf)
    __shared__ __align__(16) unsigned short Bs_[128 * 64];      // 16 KiB (single)
    const int tid = threadIdx.x;
    const int nwg = gridDim.x;
    int bid = blockIdx.x;
    if ((nwg & 7) == 0) bid = (bid & 7) * (nwg >> 3) + (bid >> 3);
    const int brow = bid / nColBlocks, bcol = bid % nColBlocks;
    const int rowBase = brow * 256, colBase = bcol * 128;
    const int lane = tid & 63, wv = tid >> 6;      // 8 waves
    const int wm = wv >> 1, wn = wv & 1;           // 4M x 2N (wave = 64x64 output)
    const int lr = lane & 15, lk = lane >> 4;
    const int sr8 = (wv << 3) + (lane >> 3);       // staging row within 64-row group
    const int ss = lane & 7;                       // staging slot

    f32x4 acc[4][4] = {};
    const int NT = K >> 6;                         // 8 K-steps

    auto stageA = [&](int buf, int kt) {           // 4 gload16 / thread (32 KiB)
        #pragma unroll
        for (int j = 0; j < 4; ++j) {
            int r = j * 64 + sr8;
            int scol = ((ss ^ (r & 7)) << 3) + kt;
            gload16(A + (size_t)(rowBase + r) * K + scol, &As_[buf][(j * 512 + (wv << 6)) * 8]);
        }
    };
    auto stageB = [&](int kt) {                    // 2 gload16 / thread (16 KiB)
        #pragma unroll
        for (int j = 0; j < 2; ++j) {
            int r = j * 64 + sr8;
            int scol = ((ss ^ (r & 7)) << 3) + kt;
            gload16(B + (size_t)(colBase + r) * K + scol, Bs_ + (j * 512 + (wv << 6)) * 8);
        }
    };

    // prologue: queue (oldest first) = A(0)[4], B(0)[2], A(1)[4]
    stageA(0, 0);
    stageB(0);
    if (NT > 1) stageA(1, 64);

    for (int t = 0; t < NT; ++t) {
        if (t + 1 < NT) { asm volatile("s_waitcnt vmcnt(4)" ::: "memory"); }
        else           { asm volatile("s_waitcnt vmcnt(0)" ::: "memory"); }
        __builtin_amdgcn_sched_barrier(0);
        __builtin_amdgcn_s_barrier();              // all waves' staging visible
        __builtin_amdgcn_sched_barrier(0);

        const unsigned short* Ab = &As_[t & 1][0];
        #pragma unroll
        for (int kk = 0; kk < 2; ++kk) {
            bf16x8 af[4], bfr[4];
            #pragma unroll
            for (int mi = 0; mi < 4; ++mi) {
                int row = wm * 64 + mi * 16 + lr;
                af[mi] = *(const bf16x8*)((const char*)Ab + row * 128 +
                                          ((kk * 64 + lk * 16) ^ ((row & 7) << 4)));
            }
            #pragma unroll
            for (int ni = 0; ni < 4; ++ni) {
                int row = wn * 64 + ni * 16 + lr;
                bfr[ni] = *(const bf16x8*)((const char*)Bs_ + row * 128 +
                                           ((kk * 64 + lk * 16) ^ ((row & 7) << 4)));
            }
            #pragma unroll
            for (int mi = 0; mi < 4; ++mi)
                #pragma unroll
                for (int ni = 0; ni < 4; ++ni)
                    acc[mi][ni] = __builtin_amdgcn_mfma_f32_16x16x32_bf16(af[mi], bfr[ni], acc[mi][ni], 0, 0, 0);
        }

        __builtin_amdgcn_sched_barrier(0);
        __builtin_amdgcn_s_barrier();              // all waves done reading this iter's LDS
        __builtin_amdgcn_sched_barrier(0);
        if (t + 1 < NT) stageB((t + 1) << 6);
        if (t + 2 < NT) stageA(t & 1, (t + 2) << 6);
    }

    // ---- epilogue: C/D layout col=lane&15, row=(lane>>4)*4+reg; branch uniform per block ----
    if (MODE == 1) {
        #pragma unroll
        for (int mi = 0; mi < 4; ++mi) {
            const int grow0 = rowBase + wm * 64 + mi * 16 + lk * 4;
            #pragma unroll
            for (int ni = 0; ni < 4; ++ni) {
                const int gcol = colBase + wn * 64 + ni * 16 + lr;
                #pragma unroll
                for (int r = 0; r < 4; ++r)
                    ((float*)Cq)[(size_t)(grow0 + r) * DMODEL + gcol] = acc[mi][ni][r] + bias[gcol];
            }
        }
    } else if (colBase < 512) {           // q: elu(q*scale)+1, row-major [tok][512] (coalesced)
        #pragma unroll
        for (int mi = 0; mi < 4; ++mi) {
            const int grow0 = rowBase + wm * 64 + mi * 16 + lk * 4;
            #pragma unroll
            for (int ni = 0; ni < 4; ++ni) {
                const int gcol = colBase + wn * 64 + ni * 16 + lr;
                #pragma unroll
                for (int r = 0; r < 4; ++r)
                    ((unsigned short*)Cq)[(size_t)(grow0 + r) * DMODEL + gcol] =
                        f2b(feat(acc[mi][ni][r] * 0.125f));
            }
        }
    } else {                              // k or v -> transposed [bh*64+d][n] via LDS bounce
        const bool isK = (colBase < 1024);
        const int hdBase = isK ? (colBase - 512) : (colBase - 1024);
        const int b_ = rowBase >> 12, n0 = rowBase & 4095;
        unsigned short* T = &As_[0][0];   // 128(hd) x 256(n) u16 = 64 KiB, As_ is dead here
        // 1) write acc -> T, XOR-swizzled (16B-granular: order-safe, 4-way-min banks)
        #pragma unroll
        for (int mi = 0; mi < 4; ++mi) {
            const int n_l0 = wm * 64 + mi * 16 + lk * 4;
            #pragma unroll
            for (int ni = 0; ni < 4; ++ni) {
                const int hd_l = wn * 64 + ni * 16 + lr;
                u16x4 o;
                if (isK) {
                    o = (u16x4){ f2b(feat(acc[mi][ni][0])), f2b(feat(acc[mi][ni][1])),
                                 f2b(feat(acc[mi][ni][2])), f2b(feat(acc[mi][ni][3])) };
                } else {
                    o = (u16x4){ f2b(acc[mi][ni][0]), f2b(acc[mi][ni][1]),
                                 f2b(acc[mi][ni][2]), f2b(acc[mi][ni][3]) };
                }
                *(u16x4*)((char*)T + hd_l * 512 + ((n_l0 * 2) ^ ((hd_l & 15) << 4))) = o;
            }
        }
        __syncthreads();
        // 2) coalesced flush: thread -> (row=hd, 128B chunk); 16B/lane, 4 lanes/line
        unsigned short* dst = isK ? Ck : Cv;
        const int row = tid >> 2;         // 0..127 (hd local)
        const int ch = tid & 3;           // 0..3   (128B chunk within row)
        unsigned short* drow = dst + (size_t)(b_ * 512 + hdBase + row) * SEQ + n0;
        #pragma unroll
        for (int i = 0; i < 8; ++i) {
            u16x8 v = *(const u16x8*)((const char*)T + row * 512 +
                                      ((ch * 128 + i * 16) ^ ((row & 15) << 4)));
            *(u16x8*)&drow[ch * 64 + i * 8] = v;
        }
    }
}

// ---------------- ctx (MFMA): ctxP[chunk][bh][d][e] = sum_n k[n][d] v[n][e]; kc via ones ----
__global__ __launch_bounds__(256) void ctx_kernel(const unsigned short* __restrict__ kT,
                                                  const unsigned short* __restrict__ vT,
                                                  float* __restrict__ ctxP,
                                                  float* __restrict__ kcP) {
    const int bh = blockIdx.x >> 3;
    const int chunk = blockIdx.x & 7;
    __shared__ __align__(16) unsigned short ks[64 * 64];
    __shared__ __align__(16) unsigned short vs[64 * 64];
    const int tid = threadIdx.x;
    const int lane = tid & 63, wv = tid >> 6;
    const int lr = lane & 15, lk = lane >> 4;
    const int xorv = (lr & 7) << 4;
    const int r_s = tid >> 3, s_s = tid & 7;
    const unsigned short* kg = kT + (size_t)bh * 64 * SEQ;
    const unsigned short* vg = vT + (size_t)bh * 64 * SEQ;

    f32x4 acc[4] = {};
    f32x4 kacc[4] = {};
    union { u16x8 u; bf16x8 b; } onesc;
    onesc.u = (u16x8){0x3F80, 0x3F80, 0x3F80, 0x3F80, 0x3F80, 0x3F80, 0x3F80, 0x3F80};
    const bf16x8 ones = onesc.b;

    for (int t = 0; t < 8; ++t) {
        const int n0 = chunk * 512 + t * 64;
        __syncthreads();                                  // protect prev-tile reads
        #pragma unroll
        for (int j = 0; j < 2; ++j) {
            int r = j * 32 + r_s;                         // d-row 0..63
            int scol = ((s_s ^ (r & 7)) << 3) + n0;       // pre-swizzled source
            gload16(kg + (size_t)r * SEQ + scol, ks + (j * 256 + (wv << 6)) * 8);
            gload16(vg + (size_t)r * SEQ + scol, vs + (j * 256 + (wv << 6)) * 8);
        }
        __syncthreads();                                  // drain gload16
        #pragma unroll
        for (int kk = 0; kk < 2; ++kk) {
            bf16x8 bfr = *(const bf16x8*)((const char*)vs + (wv * 16 + lr) * 128 + ((kk * 64 + lk * 16) ^ xorv));
            #pragma unroll
            for (int mi = 0; mi < 4; ++mi) {
                bf16x8 af = *(const bf16x8*)((const char*)ks + (mi * 16 + lr) * 128 + ((kk * 64 + lk * 16) ^ xorv));
                acc[mi] = __builtin_amdgcn_mfma_f32_16x16x32_bf16(af, bfr, acc[mi], 0, 0, 0);
                if (wv == 0)
                    kacc[mi] = __builtin_amdgcn_mfma_f32_16x16x32_bf16(af, ones, kacc[mi], 0, 0, 0);
            }
        }
    }
    float* cp = ctxP + ((size_t)chunk * NBH + bh) * 4096;
    #pragma unroll
    for (int mi = 0; mi < 4; ++mi)
        #pragma unroll
        for (int r = 0; r < 4; ++r)
            cp[(mi * 16 + lk * 4 + r) * 64 + wv * 16 + lr] = acc[mi][r];
    if (wv == 0 && lr == 0) {
        float* kp = kcP + ((size_t)chunk * NBH + bh) * 64;
        #pragma unroll
        for (int mi = 0; mi < 4; ++mi)
            #pragma unroll
            for (int r = 0; r < 4; ++r)
                kp[mi * 16 + lk * 4 + r] = kacc[mi][r];
    }
}

// ---------------- reduce: sum partials; emit ctxT hi/lo bf16 [bh][e][d] + kc fp32 ----------------
__global__ __launch_bounds__(256) void reduce_kernel(const float* __restrict__ ctxP,
                                                     const float* __restrict__ kcP,
                                                     unsigned short* __restrict__ cTh,
                                                     unsigned short* __restrict__ cTl,
                                                     float* __restrict__ kcR) {
    const int bh = blockIdx.x;
    const int t = threadIdx.x;
    #pragma unroll
    for (int p = 0; p < 4; ++p) {
        int idx = p * 256 + t;                            // f32x4 index; elems [d][e0..e0+3]
        f32x4 s = {0.f, 0.f, 0.f, 0.f};
        for (int c = 0; c < NCHUNK; ++c)
            s += ((const f32x4*)(ctxP + ((size_t)c * NBH + bh) * 4096))[idx];
        int d = idx >> 4, e0 = (idx & 15) * 4;
        #pragma unroll
        for (int j = 0; j < 4; ++j) {
            unsigned short hi = f2b(s[j]);
            cTh[(size_t)bh * 4096 + (e0 + j) * 64 + d] = hi;
            cTl[(size_t)bh * 4096 + (e0 + j) * 64 + d] = f2b(s[j] - b2f(hi));
        }
    }
    if (t < 64) {
        float s = 0.f;
        for (int c = 0; c < NCHUNK; ++c) s += kcP[((size_t)c * NBH + bh) * 64 + t];
        kcR[bh * 64 + t] = s;
    }
}

// ---------------- attn (MFMA): inner[n][h*64+e] = (q @ (ctx_hi+ctx_lo)) / (q . kc) ----------------
__global__ __launch_bounds__(256) void attn_kernel(const unsigned short* __restrict__ qF,
                                                   const unsigned short* __restrict__ cTh,
                                                   const unsigned short* __restrict__ cTl,
                                                   const float* __restrict__ kcR,
                                                   unsigned short* __restrict__ inner) {
    const int bh = blockIdx.x >> 6;
    const int rt = blockIdx.x & 63;
    const int b = bh >> 3, h = bh & 7;
    const size_t rowBase = (size_t)b * SEQ + (size_t)rt * 64;
    __shared__ __align__(16) unsigned short qs[64 * 64];
    __shared__ __align__(16) unsigned short chs[64 * 64];
    __shared__ __align__(16) unsigned short cls[64 * 64];
    __shared__ float dpart[64][4];
    __shared__ float dens[64];
    __shared__ float kcs[64];
    const int tid = threadIdx.x;
    const int lane = tid & 63, wv = tid >> 6;
    const int lr = lane & 15, lk = lane >> 4;
    const int xorv = (lr & 7) << 4;
    const int r_s = tid >> 3, s_s = tid & 7;

    #pragma unroll
    for (int j = 0; j < 2; ++j) {
        int r = j * 32 + r_s;
        int sc = (s_s ^ (r & 7)) << 3;
        gload16(qF + (rowBase + r) * DMODEL + h * 64 + sc, qs + (j * 256 + (wv << 6)) * 8);
        gload16(cTh + (size_t)bh * 4096 + r * 64 + sc, chs + (j * 256 + (wv << 6)) * 8);
        gload16(cTl + (size_t)bh * 4096 + r * 64 + sc, cls + (j * 256 + (wv << 6)) * 8);
    }
    if (tid < 64) kcs[tid] = kcR[bh * 64 + tid];
    __syncthreads();                                      // drain gload16 + kcs
    {   // denom partials: 4 d-quarters x 64 rows in parallel
        int row = tid & 63, part = tid >> 6;
        float s = 0.f;
        #pragma unroll
        for (int i = 0; i < 16; ++i) {
            int d = part * 16 + i;
            unsigned short qv = *(const unsigned short*)((const char*)qs + row * 128 + ((d * 2) ^ ((row & 7) << 4)));
            s += b2f(qv) * kcs[d];
        }
        dpart[row][part] = s;
    }
    __syncthreads();
    if (tid < 64) dens[tid] = 1e-8f + dpart[tid][0] + dpart[tid][1] + dpart[tid][2] + dpart[tid][3];
    __syncthreads();

    f32x4 acc[4] = {};
    #pragma unroll
    for (int kk = 0; kk < 2; ++kk) {
        bf16x8 af = *(const bf16x8*)((const char*)qs + (wv * 16 + lr) * 128 + ((kk * 64 + lk * 16) ^ xorv));
        #pragma unroll
        for (int ni = 0; ni < 4; ++ni) {
            bf16x8 bh_ = *(const bf16x8*)((const char*)chs + (ni * 16 + lr) * 128 + ((kk * 64 + lk * 16) ^ xorv));
            bf16x8 bl_ = *(const bf16x8*)((const char*)cls + (ni * 16 + lr) * 128 + ((kk * 64 + lk * 16) ^ xorv));
            acc[ni] = __builtin_amdgcn_mfma_f32_16x16x32_bf16(af, bh_, acc[ni], 0, 0, 0);
            acc[ni] = __builtin_amdgcn_mfma_f32_16x16x32_bf16(af, bl_, acc[ni], 0, 0, 0);
        }
    }
    #pragma unroll
    for (int ni = 0; ni < 4; ++ni)
        #pragma unroll
        for (int r = 0; r < 4; ++r) {
            int n = wv * 16 + lk * 4 + r;
            float o = acc[ni][r] / dens[n];
            inner[(rowBase + n) * DMODEL + h * 64 + ni * 16 + lr] = f2b(o);
        }
}

extern "C" void kernel_launch(void* const* d_in, const int* in_sizes, int n_in,
                              void* d_out, int out_size, void* d_ws, size_t ws_size,
                              hipStream_t stream) {
    (void)in_sizes; (void)n_in; (void)out_size; (void)ws_size;
    const float* x    = (const float*)d_in[0];
    const float* wqkv = (const float*)d_in[1];
    const float* wout = (const float*)d_in[2];
    const float* bout = (const float*)d_in[3];

    char* w = (char*)d_ws;
    // Region [0, 32MB): xB (prep->gemm0), then ctxP+kcP (ctx->reduce), then inner (attn->gemm1)
    unsigned short* xB    = (unsigned short*)(w);                 // 32768*512*2  = 33554432
    float*          ctxP  = (float*)(w);                          // 8*64*4096*4  = 8388608
    float*          kcP   = (float*)(w + 8388608);                // 8*64*64*4    = 131072
    unsigned short* inner = (unsigned short*)(w);                 // 33554432
    unsigned short* qF    = (unsigned short*)(w + 33554432);      // 32768*512*2  = 33554432
    unsigned short* kT    = (unsigned short*)(w + 67108864);      // 64*64*4096*2 = 33554432
    unsigned short* vT    = (unsigned short*)(w + 100663296);     // 33554432
    unsigned short* wqkvB = (unsigned short*)(w + 134217728);     // 1536*512*2 = 1572864
    unsigned short* woutB = (unsigned short*)(w + 135790592);     // 512*512*2  = 524288
    unsigned short* cTh   = (unsigned short*)(w + 136314880);     // 64*64*64*2   = 524288
    unsigned short* cTl   = (unsigned short*)(w + 136839168);     // 524288
    float*          kcR   = (float*)(w + 137363456);              // 64*64*4      = 16384
    // total ws usage: 137379840 bytes (< 144834560 proven available)

    hipLaunchKernelGGL(prep_kernel, dim3(2048), dim3(256), 0, stream,
                       x, wqkv, wout, xB, wqkvB, woutB);
    hipLaunchKernelGGL((gemm_kernel<0>), dim3(1536), dim3(512), 0, stream,
                       xB, wqkvB, (void*)qF, kT, vT, (const float*)nullptr,
                       NTOK, NQKV, DMODEL, 12);
    hipLaunchKernelGGL(ctx_kernel, dim3(NBH * NCHUNK), dim3(256), 0, stream, kT, vT, ctxP, kcP);
    hipLaunchKernelGGL(reduce_kernel, dim3(NBH), dim3(256), 0, stream, ctxP, kcP, cTh, cTl, kcR);
    hipLaunchKernelGGL(attn_kernel, dim3(NBH * 64), dim3(256), 0, stream, qF, cTh, cTl, kcR, inner);
    hipLaunchKernelGGL((gemm_kernel<1>), dim3(512), dim3(512), 0, stream,
                       inner, woutB, (void*)d_out, (unsigned short*)nullptr, (unsigned short*)nullptr, bout,
                       NTOK, DMODEL, DMODEL, 4);
}

// Round 14
// 146.441 us; speedup vs baseline: 1.0801x; 1.0801x over previous
//
#include <hip/hip_runtime.h>
#include <cstdint>
#include <cstddef>

typedef __bf16 bf16_t;
typedef bf16_t bf16x8 __attribute__((ext_vector_type(8)));
typedef float f32x4 __attribute__((ext_vector_type(4)));
typedef unsigned short u16x8 __attribute__((ext_vector_type(8)));
typedef unsigned short u16x4 __attribute__((ext_vector_type(4)));

#define SEQ 4096
#define BATCH 8
#define NTOK 32768      // BATCH*SEQ
#define NQKV 1536
#define DMODEL 512
#define NBH 64          // BATCH*HEADS
#define NCHUNK 8

__device__ __forceinline__ unsigned short f2b(float f) {
    union { float f; unsigned u; } c; c.f = f;
    unsigned u = c.u;
    u += 0x7fffu + ((u >> 16) & 1u);   // round-to-nearest-even
    return (unsigned short)(u >> 16);
}
__device__ __forceinline__ float b2f(unsigned short h) {
    union { unsigned u; float f; } c; c.u = ((unsigned)h) << 16;
    return c.f;
}
__device__ __forceinline__ float feat(float v) {   // elu(v)+1
    return v > 0.f ? v + 1.f : __expf(v);
}

// async global->LDS, 16B per lane; LDS dest is wave-uniform base + lane*16
__device__ __forceinline__ void gload16(const unsigned short* g, unsigned short* lds_base) {
    __builtin_amdgcn_global_load_lds((const __attribute__((address_space(1))) unsigned int*)g,
                                     (__attribute__((address_space(3))) unsigned int*)lds_base,
                                     16, 0, 0);
}

// ---------------- prep: fp32 -> bf16 for x and both weights ----------------
__global__ __launch_bounds__(256) void prep_kernel(const float* __restrict__ x,
                                                   const float* __restrict__ wqkv,
                                                   const float* __restrict__ wout,
                                                   unsigned short* __restrict__ xB,
                                                   unsigned short* __restrict__ wqkvB,
                                                   unsigned short* __restrict__ woutB) {
    const int stride = gridDim.x * 256;
    const int t0 = blockIdx.x * 256 + threadIdx.x;
    for (int j = t0; j < NTOK * DMODEL / 4; j += stride) {
        f32x4 v = ((const f32x4*)x)[j];
        u16x4 o = { f2b(v[0]), f2b(v[1]), f2b(v[2]), f2b(v[3]) };
        ((u16x4*)xB)[j] = o;
    }
    for (int j = t0; j < NQKV * DMODEL / 4; j += stride) {
        f32x4 v = ((const f32x4*)wqkv)[j];
        u16x4 o = { f2b(v[0]), f2b(v[1]), f2b(v[2]), f2b(v[3]) };
        ((u16x4*)wqkvB)[j] = o;
    }
    for (int j = t0; j < DMODEL * DMODEL / 4; j += stride) {
        f32x4 v = ((const f32x4*)wout)[j];
        u16x4 o = { f2b(v[0]), f2b(v[1]), f2b(v[2]), f2b(v[3]) };
        ((u16x4*)woutB)[j] = o;
    }
}

// ---------------- MFMA GEMM: C = A @ B^T, A bf16 [M][K], B bf16 [N][K] ----------------
// 256x128 tile, 8 waves (4M x 2N), BK=64. Counted-vmcnt pipeline (T4):
//   A double-buffered (HBM latency, prefetch 2 iters ahead),
//   B single-buffered (L2-resident weights, prefetch 1 iter ahead),
//   raw s_barrier + vmcnt(4) in steady state -- NO vmcnt(0) drain in the loop.
// LDS = 80 KiB -> 2 blocks/CU. T2 XOR-swizzle (0 conflicts), T1 XCD swizzle.
// MODE 0: feature-map epilogue -> qF [tok][512] bf16; kT/vT [bh][d][4096] bf16 (transposed)
// MODE 1: +bias epilogue -> fp32 out [tok][512]   (Ck/Cv unused)
template <int MODE>
__global__ __launch_bounds__(512) void gemm_kernel(const unsigned short* __restrict__ A,
                                                   const unsigned short* __restrict__ B,
                                                   void* __restrict__ Cq,
                                                   unsigned short* __restrict__ Ck,
                                                   unsigned short* __restrict__ Cv,
                                                   const float* __restrict__ bias,
                                                   int M, int N, int K, int nColBlocks) {
    __shared__ __align__(16) unsigned short As_[2][256 * 64];   // 64 KiB (dbuf)
    __shared__ __align__(16) unsigned short Bs_[128 * 64];      // 16 KiB (single)
    const int tid = threadIdx.x;
    const int nwg = gridDim.x;
    int bid = blockIdx.x;
    if ((nwg & 7) == 0) bid = (bid & 7) * (nwg >> 3) + (bid >> 3);
    const int brow = bid / nColBlocks, bcol = bid % nColBlocks;
    const int rowBase = brow * 256, colBase = bcol * 128;
    const int lane = tid & 63, wv = tid >> 6;      // 8 waves
    const int wm = wv >> 1, wn = wv & 1;           // 4M x 2N (wave = 64x64 output)
    const int lr = lane & 15, lk = lane >> 4;
    const int xorv = (lr & 7) << 4;
    const int sr8 = (wv << 3) + (lane >> 3);       // staging row within 64-row group
    const int ss = lane & 7;                       // staging slot

    f32x4 acc[4][4] = {};
    const int NT = K >> 6;                         // 8 K-steps

    // ---- staging helpers: linear LDS dest (wave-uniform base), pre-swizzled source ----
    auto stageA = [&](int buf, int kt) {           // 4 gload16 / thread (32 KiB)
        #pragma unroll
        for (int j = 0; j < 4; ++j) {
            int r = j * 64 + sr8;
            int scol = ((ss ^ (r & 7)) << 3) + kt;
            gload16(A + (size_t)(rowBase + r) * K + scol, &As_[buf][(j * 512 + (wv << 6)) * 8]);
        }
    };
    auto stageB = [&](int kt) {                    // 2 gload16 / thread (16 KiB)
        #pragma unroll
        for (int j = 0; j < 2; ++j) {
            int r = j * 64 + sr8;
            int scol = ((ss ^ (r & 7)) << 3) + kt;
            gload16(B + (size_t)(colBase + r) * K + scol, Bs_ + (j * 512 + (wv << 6)) * 8);
        }
    };

    // prologue: queue (oldest first) = A(0)[4], B(0)[2], A(1)[4]
    stageA(0, 0);
    stageB(0);
    if (NT > 1) stageA(1, 64);

    for (int t = 0; t < NT; ++t) {
        // wait for tile t's A(4)+B(2) = oldest 6; leave A(t+1)'s 4 in flight
        if (t + 1 < NT) { asm volatile("s_waitcnt vmcnt(4)" ::: "memory"); }
        else           { asm volatile("s_waitcnt vmcnt(0)" ::: "memory"); }
        __builtin_amdgcn_sched_barrier(0);
        __builtin_amdgcn_s_barrier();              // all waves' staging visible
        __builtin_amdgcn_sched_barrier(0);

        const unsigned short* Ab = &As_[t & 1][0];
        #pragma unroll
        for (int kk = 0; kk < 2; ++kk) {
            bf16x8 af[4], bfr[4];
            #pragma unroll
            for (int mi = 0; mi < 4; ++mi) {
                int row = wm * 64 + mi * 16 + lr;
                af[mi] = *(const bf16x8*)((const char*)Ab + row * 128 + ((kk * 64 + lk * 16) ^ xorv));
            }
            #pragma unroll
            for (int ni = 0; ni < 4; ++ni) {
                int row = wn * 64 + ni * 16 + lr;
                bfr[ni] = *(const bf16x8*)((const char*)Bs_ + row * 128 + ((kk * 64 + lk * 16) ^ xorv));
            }
            #pragma unroll
            for (int mi = 0; mi < 4; ++mi)
                #pragma unroll
                for (int ni = 0; ni < 4; ++ni)
                    acc[mi][ni] = __builtin_amdgcn_mfma_f32_16x16x32_bf16(af[mi], bfr[ni], acc[mi][ni], 0, 0, 0);
        }

        __builtin_amdgcn_sched_barrier(0);
        __builtin_amdgcn_s_barrier();              // all waves done reading this iter's LDS
        __builtin_amdgcn_sched_barrier(0);
        if (t + 1 < NT) stageB((t + 1) << 6);      // into Bs_ (just freed)
        if (t + 2 < NT) stageA(t & 1, (t + 2) << 6); // into buf just freed
    }

    // ---- epilogue: C/D layout col=lane&15, row=(lane>>4)*4+reg; branch uniform per block ----
    if (MODE == 1) {
        #pragma unroll
        for (int mi = 0; mi < 4; ++mi) {
            const int grow0 = rowBase + wm * 64 + mi * 16 + lk * 4;
            #pragma unroll
            for (int ni = 0; ni < 4; ++ni) {
                const int gcol = colBase + wn * 64 + ni * 16 + lr;
                #pragma unroll
                for (int r = 0; r < 4; ++r)
                    ((float*)Cq)[(size_t)(grow0 + r) * DMODEL + gcol] = acc[mi][ni][r] + bias[gcol];
            }
        }
    } else if (colBase < 512) {           // q: elu(q*scale)+1, row-major [tok][512]
        #pragma unroll
        for (int mi = 0; mi < 4; ++mi) {
            const int grow0 = rowBase + wm * 64 + mi * 16 + lk * 4;
            #pragma unroll
            for (int ni = 0; ni < 4; ++ni) {
                const int gcol = colBase + wn * 64 + ni * 16 + lr;
                #pragma unroll
                for (int r = 0; r < 4; ++r)
                    ((unsigned short*)Cq)[(size_t)(grow0 + r) * DMODEL + gcol] =
                        f2b(feat(acc[mi][ni][r] * 0.125f));
            }
        }
    } else if (colBase < 1024) {          // k: elu(k)+1 -> kT [bh*64+d][n]
        #pragma unroll
        for (int mi = 0; mi < 4; ++mi) {
            const int grow0 = rowBase + wm * 64 + mi * 16 + lk * 4;
            const int b_ = grow0 >> 12, n0 = grow0 & 4095;
            #pragma unroll
            for (int ni = 0; ni < 4; ++ni) {
                const int hd = colBase - 512 + wn * 64 + ni * 16 + lr;
                u16x4 o = { f2b(feat(acc[mi][ni][0])), f2b(feat(acc[mi][ni][1])),
                            f2b(feat(acc[mi][ni][2])), f2b(feat(acc[mi][ni][3])) };
                *(u16x4*)&Ck[((size_t)(b_ * 512 + hd)) * SEQ + n0] = o;
            }
        }
    } else {                              // v raw -> vT [bh*64+d][n]
        #pragma unroll
        for (int mi = 0; mi < 4; ++mi) {
            const int grow0 = rowBase + wm * 64 + mi * 16 + lk * 4;
            const int b_ = grow0 >> 12, n0 = grow0 & 4095;
            #pragma unroll
            for (int ni = 0; ni < 4; ++ni) {
                const int hd = colBase - 1024 + wn * 64 + ni * 16 + lr;
                u16x4 o = { f2b(acc[mi][ni][0]), f2b(acc[mi][ni][1]),
                            f2b(acc[mi][ni][2]), f2b(acc[mi][ni][3]) };
                *(u16x4*)&Cv[((size_t)(b_ * 512 + hd)) * SEQ + n0] = o;
            }
        }
    }
}

// ---------------- ctx (MFMA): ctxP[chunk][bh][d][e] = sum_n k[n][d] v[n][e]; kc via ones ----
__global__ __launch_bounds__(256) void ctx_kernel(const unsigned short* __restrict__ kT,
                                                  const unsigned short* __restrict__ vT,
                                                  float* __restrict__ ctxP,
                                                  float* __restrict__ kcP) {
    const int bh = blockIdx.x >> 3;
    const int chunk = blockIdx.x & 7;
    __shared__ __align__(16) unsigned short ks[64 * 64];
    __shared__ __align__(16) unsigned short vs[64 * 64];
    const int tid = threadIdx.x;
    const int lane = tid & 63, wv = tid >> 6;
    const int lr = lane & 15, lk = lane >> 4;
    const int xorv = (lr & 7) << 4;
    const int r_s = tid >> 3, s_s = tid & 7;
    const unsigned short* kg = kT + (size_t)bh * 64 * SEQ;
    const unsigned short* vg = vT + (size_t)bh * 64 * SEQ;

    f32x4 acc[4] = {};
    f32x4 kacc[4] = {};
    union { u16x8 u; bf16x8 b; } onesc;
    onesc.u = (u16x8){0x3F80, 0x3F80, 0x3F80, 0x3F80, 0x3F80, 0x3F80, 0x3F80, 0x3F80};
    const bf16x8 ones = onesc.b;

    for (int t = 0; t < 8; ++t) {
        const int n0 = chunk * 512 + t * 64;
        __syncthreads();                                  // protect prev-tile reads
        #pragma unroll
        for (int j = 0; j < 2; ++j) {
            int r = j * 32 + r_s;                         // d-row 0..63
            int scol = ((s_s ^ (r & 7)) << 3) + n0;       // pre-swizzled source
            gload16(kg + (size_t)r * SEQ + scol, ks + (j * 256 + (wv << 6)) * 8);
            gload16(vg + (size_t)r * SEQ + scol, vs + (j * 256 + (wv << 6)) * 8);
        }
        __syncthreads();                                  // drain gload16
        #pragma unroll
        for (int kk = 0; kk < 2; ++kk) {
            bf16x8 bfr = *(const bf16x8*)((const char*)vs + (wv * 16 + lr) * 128 + ((kk * 64 + lk * 16) ^ xorv));
            #pragma unroll
            for (int mi = 0; mi < 4; ++mi) {
                bf16x8 af = *(const bf16x8*)((const char*)ks + (mi * 16 + lr) * 128 + ((kk * 64 + lk * 16) ^ xorv));
                acc[mi] = __builtin_amdgcn_mfma_f32_16x16x32_bf16(af, bfr, acc[mi], 0, 0, 0);
                if (wv == 0)
                    kacc[mi] = __builtin_amdgcn_mfma_f32_16x16x32_bf16(af, ones, kacc[mi], 0, 0, 0);
            }
        }
    }
    float* cp = ctxP + ((size_t)chunk * NBH + bh) * 4096;
    #pragma unroll
    for (int mi = 0; mi < 4; ++mi)
        #pragma unroll
        for (int r = 0; r < 4; ++r)
            cp[(mi * 16 + lk * 4 + r) * 64 + wv * 16 + lr] = acc[mi][r];
    if (wv == 0 && lr == 0) {
        float* kp = kcP + ((size_t)chunk * NBH + bh) * 64;
        #pragma unroll
        for (int mi = 0; mi < 4; ++mi)
            #pragma unroll
            for (int r = 0; r < 4; ++r)
                kp[mi * 16 + lk * 4 + r] = kacc[mi][r];
    }
}

// ---------------- reduce: sum partials; emit ctxT hi/lo bf16 [bh][e][d] + kc fp32 ----------------
__global__ __launch_bounds__(256) void reduce_kernel(const float* __restrict__ ctxP,
                                                     const float* __restrict__ kcP,
                                                     unsigned short* __restrict__ cTh,
                                                     unsigned short* __restrict__ cTl,
                                                     float* __restrict__ kcR) {
    const int bh = blockIdx.x;
    const int t = threadIdx.x;
    #pragma unroll
    for (int p = 0; p < 4; ++p) {
        int idx = p * 256 + t;                            // f32x4 index; elems [d][e0..e0+3]
        f32x4 s = {0.f, 0.f, 0.f, 0.f};
        for (int c = 0; c < NCHUNK; ++c)
            s += ((const f32x4*)(ctxP + ((size_t)c * NBH + bh) * 4096))[idx];
        int d = idx >> 4, e0 = (idx & 15) * 4;
        #pragma unroll
        for (int j = 0; j < 4; ++j) {
            unsigned short hi = f2b(s[j]);
            cTh[(size_t)bh * 4096 + (e0 + j) * 64 + d] = hi;
            cTl[(size_t)bh * 4096 + (e0 + j) * 64 + d] = f2b(s[j] - b2f(hi));
        }
    }
    if (t < 64) {
        float s = 0.f;
        for (int c = 0; c < NCHUNK; ++c) s += kcP[((size_t)c * NBH + bh) * 64 + t];
        kcR[bh * 64 + t] = s;
    }
}

// ---------------- attn (MFMA): inner[n][h*64+e] = (q @ (ctx_hi+ctx_lo)) / (q . kc) ----------------
__global__ __launch_bounds__(256) void attn_kernel(const unsigned short* __restrict__ qF,
                                                   const unsigned short* __restrict__ cTh,
                                                   const unsigned short* __restrict__ cTl,
                                                   const float* __restrict__ kcR,
                                                   unsigned short* __restrict__ inner) {
    const int bh = blockIdx.x >> 6;
    const int rt = blockIdx.x & 63;
    const int b = bh >> 3, h = bh & 7;
    const size_t rowBase = (size_t)b * SEQ + (size_t)rt * 64;
    __shared__ __align__(16) unsigned short qs[64 * 64];
    __shared__ __align__(16) unsigned short chs[64 * 64];
    __shared__ __align__(16) unsigned short cls[64 * 64];
    __shared__ float dpart[64][4];
    __shared__ float dens[64];
    __shared__ float kcs[64];
    const int tid = threadIdx.x;
    const int lane = tid & 63, wv = tid >> 6;
    const int lr = lane & 15, lk = lane >> 4;
    const int xorv = (lr & 7) << 4;
    const int r_s = tid >> 3, s_s = tid & 7;

    #pragma unroll
    for (int j = 0; j < 2; ++j) {
        int r = j * 32 + r_s;
        int sc = (s_s ^ (r & 7)) << 3;
        gload16(qF + (rowBase + r) * DMODEL + h * 64 + sc, qs + (j * 256 + (wv << 6)) * 8);
        gload16(cTh + (size_t)bh * 4096 + r * 64 + sc, chs + (j * 256 + (wv << 6)) * 8);
        gload16(cTl + (size_t)bh * 4096 + r * 64 + sc, cls + (j * 256 + (wv << 6)) * 8);
    }
    if (tid < 64) kcs[tid] = kcR[bh * 64 + tid];
    __syncthreads();                                      // drain gload16 + kcs
    {   // denom partials: 4 d-quarters x 64 rows in parallel
        int row = tid & 63, part = tid >> 6;
        float s = 0.f;
        #pragma unroll
        for (int i = 0; i < 16; ++i) {
            int d = part * 16 + i;
            unsigned short qv = *(const unsigned short*)((const char*)qs + row * 128 + ((d * 2) ^ ((row & 7) << 4)));
            s += b2f(qv) * kcs[d];
        }
        dpart[row][part] = s;
    }
    __syncthreads();
    if (tid < 64) dens[tid] = 1e-8f + dpart[tid][0] + dpart[tid][1] + dpart[tid][2] + dpart[tid][3];
    __syncthreads();

    f32x4 acc[4] = {};
    #pragma unroll
    for (int kk = 0; kk < 2; ++kk) {
        bf16x8 af = *(const bf16x8*)((const char*)qs + (wv * 16 + lr) * 128 + ((kk * 64 + lk * 16) ^ xorv));
        #pragma unroll
        for (int ni = 0; ni < 4; ++ni) {
            bf16x8 bh_ = *(const bf16x8*)((const char*)chs + (ni * 16 + lr) * 128 + ((kk * 64 + lk * 16) ^ xorv));
            bf16x8 bl_ = *(const bf16x8*)((const char*)cls + (ni * 16 + lr) * 128 + ((kk * 64 + lk * 16) ^ xorv));
            acc[ni] = __builtin_amdgcn_mfma_f32_16x16x32_bf16(af, bh_, acc[ni], 0, 0, 0);
            acc[ni] = __builtin_amdgcn_mfma_f32_16x16x32_bf16(af, bl_, acc[ni], 0, 0, 0);
        }
    }
    #pragma unroll
    for (int ni = 0; ni < 4; ++ni)
        #pragma unroll
        for (int r = 0; r < 4; ++r) {
            int n = wv * 16 + lk * 4 + r;
            float o = acc[ni][r] / dens[n];
            inner[(rowBase + n) * DMODEL + h * 64 + ni * 16 + lr] = f2b(o);
        }
}

extern "C" void kernel_launch(void* const* d_in, const int* in_sizes, int n_in,
                              void* d_out, int out_size, void* d_ws, size_t ws_size,
                              hipStream_t stream) {
    (void)in_sizes; (void)n_in; (void)out_size; (void)ws_size;
    const float* x    = (const float*)d_in[0];
    const float* wqkv = (const float*)d_in[1];
    const float* wout = (const float*)d_in[2];
    const float* bout = (const float*)d_in[3];

    char* w = (char*)d_ws;
    // Region [0, 32MB): xB (prep->gemm0), then ctxP+kcP (ctx->reduce), then inner (attn->gemm1)
    unsigned short* xB    = (unsigned short*)(w);                 // 32768*512*2  = 33554432
    float*          ctxP  = (float*)(w);                          // 8*64*4096*4  = 8388608
    float*          kcP   = (float*)(w + 8388608);                // 8*64*64*4    = 131072
    unsigned short* inner = (unsigned short*)(w);                 // 33554432
    unsigned short* qF    = (unsigned short*)(w + 33554432);      // 32768*512*2  = 33554432
    unsigned short* kT    = (unsigned short*)(w + 67108864);      // 64*64*4096*2 = 33554432
    unsigned short* vT    = (unsigned short*)(w + 100663296);     // 33554432
    unsigned short* wqkvB = (unsigned short*)(w + 134217728);     // 1536*512*2 = 1572864
    unsigned short* woutB = (unsigned short*)(w + 135790592);     // 512*512*2  = 524288
    unsigned short* cTh   = (unsigned short*)(w + 136314880);     // 64*64*64*2   = 524288
    unsigned short* cTl   = (unsigned short*)(w + 136839168);     // 524288
    float*          kcR   = (float*)(w + 137363456);              // 64*64*4      = 16384
    // total ws usage: 137379840 bytes (< 144834560 proven available)

    hipLaunchKernelGGL(prep_kernel, dim3(2048), dim3(256), 0, stream,
                       x, wqkv, wout, xB, wqkvB, woutB);
    hipLaunchKernelGGL((gemm_kernel<0>), dim3(1536), dim3(512), 0, stream,
                       xB, wqkvB, (void*)qF, kT, vT, (const float*)nullptr,
                       NTOK, NQKV, DMODEL, 12);
    hipLaunchKernelGGL(ctx_kernel, dim3(NBH * NCHUNK), dim3(256), 0, stream, kT, vT, ctxP, kcP);
    hipLaunchKernelGGL(reduce_kernel, dim3(NBH), dim3(256), 0, stream, ctxP, kcP, cTh, cTl, kcR);
    hipLaunchKernelGGL(attn_kernel, dim3(NBH * 64), dim3(256), 0, stream, qF, cTh, cTl, kcR, inner);
    hipLaunchKernelGGL((gemm_kernel<1>), dim3(512), dim3(512), 0, stream,
                       inner, woutB, (void*)d_out, (unsigned short*)nullptr, (unsigned short*)nullptr, bout,
                       NTOK, DMODEL, DMODEL, 4);
}